// Round 12
// baseline (199.849 us; speedup 1.0000x reference)
//
#include <hip/hip_runtime.h>
#include <stdint.h>

// Problem constants
#define BB 4
#define SS 1024
#define HIDD 1024
#define NH 16
#define DHH 64

#define LOG2E 1.44269504f
#define MOFF  28.8539008f   // 20 * log2(e)

typedef __attribute__((ext_vector_type(8))) short bf16x8;
typedef __attribute__((ext_vector_type(4))) float fx4;
typedef __attribute__((ext_vector_type(4))) int ix4;

__device__ __forceinline__ float bf2f(uint16_t u) {
    union { uint32_t u; float f; } x; x.u = ((uint32_t)u) << 16; return x.f;
}
__device__ __forceinline__ uint16_t f2bf(float f) {   // RNE
    uint32_t u = __builtin_bit_cast(uint32_t, f);
    u = u + 0x7fffu + ((u >> 16) & 1u);
    return (uint16_t)(u >> 16);
}
__device__ __forceinline__ uint32_t pk_bf16(float lo, float hi) {
    uint32_t r;
    asm volatile("v_cvt_pk_bf16_f32 %0, %1, %2" : "=v"(r) : "v"(lo), "v"(hi));
    return r;
}
__device__ __forceinline__ float exp2_hw(float x) {   // 2^x, single VALU op
    float r;
    asm("v_exp_f32 %0, %1" : "=v"(r) : "v"(x));
    return r;
}
__device__ __forceinline__ bf16x8 mk_frag(uint32_t u0, uint32_t u1, uint32_t u2, uint32_t u3) {
    ix4 v = { (int)u0, (int)u1, (int)u2, (int)u3 };
    return __builtin_bit_cast(bf16x8, v);
}
__device__ __forceinline__ uint4 pk8(float4 f0, float4 f1) {
    uint4 u;
    u.x = pk_bf16(f0.x, f0.y);
    u.y = pk_bf16(f0.z, f0.w);
    u.z = pk_bf16(f1.x, f1.y);
    u.w = pk_bf16(f1.z, f1.w);
    return u;
}

// ---------------------------------------------------------------- cvt f32->bf16 (Wrk only; r6-verified)
__global__ __launch_bounds__(256) void cvt_kernel(const float* __restrict__ in,
                                                  uint16_t* __restrict__ out, int n) {
    int i = (blockIdx.x * 256 + threadIdx.x) * 4;
    if (i < n) {
        float4 v = *(const float4*)(in + i);
        uint2 p;
        p.x = pk_bf16(v.x, v.y);
        p.y = pk_bf16(v.z, v.w);
        *(uint2*)(out + i) = p;
    }
}

// ---------------------------------------------------------------- projection GEMM (3 in one launch)
// C[m,n] = sum_k X[m,k] * W[n,k] + bias[n]; f32 inputs, cvt-to-bf16 fused into
// LDS staging (identical RNE values as the old cvt_all -> bit-identical math).
// SERIAL staging structure — r8-verified; reg-prefetch spills (r4/r7/r11).
// z==0 (Q): out bf16 [bh][s][d], PRESCALED by log2(e)
// z==1 (K): out bf16 [bh][s][d]
// z==2 (V): out bf16 [bh][d][s]  (transposed epilogue)
__global__ __launch_bounds__(256) void proj_gemm3(const float* __restrict__ X,
                                                  const float* __restrict__ Wq,
                                                  const float* __restrict__ Wk,
                                                  const float* __restrict__ Wv,
                                                  const float* __restrict__ bq,
                                                  const float* __restrict__ bk,
                                                  const float* __restrict__ bv,
                                                  uint16_t* __restrict__ oq,
                                                  uint16_t* __restrict__ ok,
                                                  uint16_t* __restrict__ ov) {
    const int z = blockIdx.z;
    const float* W = (z == 0) ? Wq : (z == 1) ? Wk : Wv;
    const float* bias = (z == 0) ? bq : (z == 1) ? bk : bv;
    uint16_t* out = (z == 0) ? oq : (z == 1) ? ok : ov;
    const float scl = (z == 0) ? LOG2E : 1.0f;

    __shared__ uint16_t Alds[128 * 64];  // [row m][k], XOR-swizzled ^((m&7)<<4)
    __shared__ uint16_t Blds[128 * 64];  // [row n][k]
    const int tid = threadIdx.x;
    const int lane = tid & 63;
    const int wvi = tid >> 6;
    const int q16 = lane & 15;
    const int hh = lane >> 4;
    const int m0 = blockIdx.x * 128;
    const int n0 = blockIdx.y * 128;
    const int wr = wvi >> 1, wc = wvi & 1;

    fx4 zero4 = { 0.f, 0.f, 0.f, 0.f };
    fx4 acc[4][4];
    #pragma unroll
    for (int a = 0; a < 4; a++)
        #pragma unroll
        for (int c = 0; c < 4; c++) acc[a][c] = zero4;

    const int srow = tid >> 1, shalf = tid & 1;
    for (int k0 = 0; k0 < HIDD; k0 += 64) {
        // stage: read f32, cvt bf16 in-reg, write LDS (serial; no cross-iter prefetch)
        const float* gA = X + (size_t)(m0 + srow) * HIDD + k0 + shalf * 32;
        const float* gB = W + (size_t)(n0 + srow) * HIDD + k0 + shalf * 32;
        #pragma unroll
        for (int i = 0; i < 4; i++) {
            float4 a0 = *(const float4*)(gA + i * 8);
            float4 a1 = *(const float4*)(gA + i * 8 + 4);
            float4 b0 = *(const float4*)(gB + i * 8);
            float4 b1 = *(const float4*)(gB + i * 8 + 4);
            uint32_t bo = (uint32_t)((shalf * 64 + i * 16) ^ ((srow & 7) << 4));
            *(uint4*)((char*)Alds + srow * 128 + bo) = pk8(a0, a1);
            *(uint4*)((char*)Blds + srow * 128 + bo) = pk8(b0, b1);
        }
        __syncthreads();
        #pragma unroll
        for (int kk = 0; kk < 2; kk++) {
            bf16x8 af[4], bfr[4];
            #pragma unroll
            for (int mi = 0; mi < 4; mi++) {
                int mr = wr * 64 + mi * 16 + q16;
                af[mi] = *(const bf16x8*)((char*)Alds + mr * 128 + ((kk * 64 + hh * 16) ^ ((mr & 7) << 4)));
            }
            #pragma unroll
            for (int ni = 0; ni < 4; ni++) {
                int nr = wc * 64 + ni * 16 + q16;
                bfr[ni] = *(const bf16x8*)((char*)Blds + nr * 128 + ((kk * 64 + hh * 16) ^ ((nr & 7) << 4)));
            }
            #pragma unroll
            for (int mi = 0; mi < 4; mi++)
                #pragma unroll
                for (int ni = 0; ni < 4; ni++)
                    acc[mi][ni] = __builtin_amdgcn_mfma_f32_16x16x32_bf16(af[mi], bfr[ni], acc[mi][ni], 0, 0, 0);
        }
        __syncthreads();
    }

    if (z < 2) {
        // epilogue: C[m, n] -> out[b][h][s][d], bf16 (Q prescaled)
        #pragma unroll
        for (int ni = 0; ni < 4; ni++) {
            int n = n0 + wc * 64 + ni * 16 + q16;
            float bvv = bias[n];
            int h = n >> 6, d = n & 63;
            #pragma unroll
            for (int mi = 0; mi < 4; mi++) {
                #pragma unroll
                for (int r = 0; r < 4; r++) {
                    int m = m0 + wr * 64 + mi * 16 + 4 * hh + r;
                    int b = m >> 10, s = m & 1023;
                    out[(size_t)b * (NH * SS * DHH) + (size_t)h * (SS * DHH) + s * DHH + d] =
                        f2bf((acc[mi][ni][r] + bvv) * scl);
                }
            }
        }
    } else {
        // epilogue: C[m, n] -> V^T [bh][d][s]; r-values are s-consecutive -> uint2
        int b = m0 >> 10;                      // blocks never straddle a batch (128 | 1024)
        int sbase = (m0 & 1023) + wr * 64;
        #pragma unroll
        for (int ni = 0; ni < 4; ni++) {
            int n = n0 + wc * 64 + ni * 16 + q16;
            float bvv = bias[n];
            int h = n >> 6, d = n & 63;
            uint16_t* base = out + ((size_t)(b * 16 + h) * 64 + d) * SS + sbase;
            #pragma unroll
            for (int mi = 0; mi < 4; mi++) {
                uint2 pp;
                pp.x = pk_bf16(acc[mi][ni][0] + bvv, acc[mi][ni][1] + bvv);
                pp.y = pk_bf16(acc[mi][ni][2] + bvv, acc[mi][ni][3] + bvv);
                *(uint2*)(base + mi * 16 + 4 * hh) = pp;
            }
        }
    }
}

// ---------------------------------------------------------------- fused attention
// BYTE-IDENTICAL to the round-8 verified kernel (116.1 µs, absmax 0.043).
__global__ __launch_bounds__(256) void attn_kernel(
    const uint16_t* __restrict__ qg,   // [BH][S][64]  (prescaled by log2e)
    const uint16_t* __restrict__ kg,   // [BH][S][64]
    const uint16_t* __restrict__ vtg,  // [BH][64][S]
    const float* __restrict__ amask,   // [B][S]
    const uint16_t* __restrict__ Wrkb, // [129][64] bf16
    const float* __restrict__ Wrv,     // [64][129]
    float* __restrict__ out)           // [B][S][NH*64]
{
    __shared__ __align__(16) char smem[37888];
    uint16_t* Klds = (uint16_t*)smem;                           // [64][64] swz, 8192 B
    uint16_t* Vlds = (uint16_t*)(smem + 8192);                  // [64][64] swz, 8192 B
    uint16_t (*sband)[136] = (uint16_t (*)[136])(smem + 16384); // 17408 B
    float* maskf = (float*)(smem + 33792);                      // 4096 B f32 prescaled bias

    const int tid = threadIdx.x;
    const int lane = tid & 63;
    const int wv = tid >> 6;
    const int q16 = lane & 15;
    const int hh = lane >> 4;
    const int id = blockIdx.y * 16 + blockIdx.x;
    const int xcd = id & 7, slot = id >> 3;
    const int bh = xcd + 8 * (slot >> 4);
    const int qt = slot & 15;
    const int b = bh >> 4;
    const int h = bh & 15;
    const int q0 = qt * 64;
    const int ql = wv * 16 + q16;
    const int qglob = q0 + ql;

    const uint16_t* qbh = qg + (size_t)bh * (SS * 64);
    const uint16_t* kbh = kg + (size_t)bh * (SS * 64);
    const uint16_t* vbh = vtg + (size_t)bh * (64 * SS);

    bf16x8 qf[2];
    #pragma unroll
    for (int ks = 0; ks < 2; ks++)
        qf[ks] = *(const bf16x8*)(qbh + (size_t)qglob * 64 + ks * 32 + hh * 8);

    const int srow = tid >> 2, spart = tid & 3;
    const uint32_t sb0 = (uint32_t)((spart * 32) ^ ((srow & 7) << 4));
    const uint32_t sb1 = (uint32_t)((spart * 32 + 16) ^ ((srow & 7) << 4));
    const uint16_t* gk0 = kbh + (size_t)srow * 64 + spart * 16;
    const uint16_t* gv0 = vbh + (size_t)srow * SS + spart * 16;
    uint4 ka  = *(const uint4*)gk0;
    uint4 kb2 = *(const uint4*)(gk0 + 8);
    uint4 va  = *(const uint4*)gv0;
    uint4 vb2 = *(const uint4*)(gv0 + 8);

    for (int i = tid * 4; i < SS; i += 1024) {
        float4 mv = *(const float4*)(amask + b * SS + i);
        fx4 o;
        o[0] = (1.0f - mv.x) * -2.0e38f - MOFF;
        o[1] = (1.0f - mv.y) * -2.0e38f - MOFF;
        o[2] = (1.0f - mv.z) * -2.0e38f - MOFF;
        o[3] = (1.0f - mv.w) * -2.0e38f - MOFF;
        *(fx4*)&maskf[i] = o;
    }

    #pragma unroll 1
    for (int wg = 0; wg < 9; wg++) {
        fx4 a = { 0.f, 0.f, 0.f, 0.f };
        int wrow = wg * 16 + q16; if (wrow > 128) wrow = 128;
        #pragma unroll
        for (int ks = 0; ks < 2; ks++) {
            bf16x8 af = *(const bf16x8*)(Wrkb + wrow * 64 + ks * 32 + hh * 8);
            a = __builtin_amdgcn_mfma_f32_16x16x32_bf16(af, qf[ks], a, 0, 0, 0);
        }
        if (wg < 8) {
            uint2 pp;
            pp.x = pk_bf16(a[0], a[1]);
            pp.y = pk_bf16(a[2], a[3]);
            *(uint2*)&sband[ql][wg * 16 + 4 * hh] = pp;
        } else if (hh == 0) {
            sband[ql][128] = f2bf(a[0]);
        }
    }
    if (qt == 0 || qt == 15) {
        int oend = hh * 33 + 33; if (oend > 129) oend = 129;
        for (int o = hh * 33; o < oend; o++) {
            int col = qglob + o - 64;
            if (col < 0 || col >= SS) sband[ql][o] = 0xff7f;
        }
    }
    __syncthreads();

    float lsum = 0.f;
    fx4 acc[4];
    #pragma unroll
    for (int dg = 0; dg < 4; dg++) acc[dg] = fx4{ 0.f, 0.f, 0.f, 0.f };

    const int srcA = q16 + 16 * ((2 * hh) & 3);
    const int srcB = q16 + 16 * ((2 * hh + 1) & 3);
    const bool lo = (hh < 2);

    for (int jt = 0; jt < 16; jt++) {
        *(uint4*)((char*)Klds + srow * 128 + sb0) = ka;
        *(uint4*)((char*)Klds + srow * 128 + sb1) = kb2;
        *(uint4*)((char*)Vlds + srow * 128 + sb0) = va;
        *(uint4*)((char*)Vlds + srow * 128 + sb1) = vb2;
        __syncthreads();

        if (jt < 15) {
            ka  = *(const uint4*)(gk0 + (size_t)(jt + 1) * 4096);
            kb2 = *(const uint4*)(gk0 + (size_t)(jt + 1) * 4096 + 8);
            va  = *(const uint4*)(gv0 + (jt + 1) * 64);
            vb2 = *(const uint4*)(gv0 + (jt + 1) * 64 + 8);
        }

        const int dj = jt - qt;
        const bool band = (dj >= -1) && (dj <= 1);
        uint32_t pk[4][2];
        #pragma unroll
        for (int mg = 0; mg < 4; mg++) {
            int mr = mg * 16 + q16;
            bf16x8 kf0 = *(const bf16x8*)((char*)Klds + mr * 128 + ((hh * 16) ^ ((mr & 7) << 4)));
            bf16x8 kf1 = *(const bf16x8*)((char*)Klds + mr * 128 + ((64 + hh * 16) ^ ((mr & 7) << 4)));
            fx4 s4 = { 0.f, 0.f, 0.f, 0.f };
            s4 = __builtin_amdgcn_mfma_f32_16x16x32_bf16(kf0, qf[0], s4, 0, 0, 0);
            s4 = __builtin_amdgcn_mfma_f32_16x16x32_bf16(kf1, qf[1], s4, 0, 0, 0);
            int mb = jt * 64 + mg * 16 + 4 * hh;
            fx4 mk4 = *(const fx4*)&maskf[mb];
            float p[4];
            #pragma unroll
            for (int r = 0; r < 4; r++) {
                int m = mb + r;
                float s = s4[r] + mk4[r];
                int o = m - qglob + 64;
                bool inb = band && (o >= 0) && (o <= 128);
                if (inb) {
                    s += bf2f(sband[ql][o]);
                    sband[ql][o] = f2bf(s + MOFF);
                }
                p[r] = exp2_hw(s);
            }
            lsum += (p[0] + p[1]) + (p[2] + p[3]);
            pk[mg][0] = pk_bf16(p[0], p[1]);
            pk[mg][1] = pk_bf16(p[2], p[3]);
        }

        #pragma unroll
        for (int ks = 0; ks < 2; ks++) {
            uint32_t a0 = (uint32_t)__shfl((int)pk[2 * ks][0], srcA);
            uint32_t b0 = (uint32_t)__shfl((int)pk[2 * ks + 1][0], srcA);
            uint32_t a1 = (uint32_t)__shfl((int)pk[2 * ks][1], srcA);
            uint32_t b1 = (uint32_t)__shfl((int)pk[2 * ks + 1][1], srcA);
            uint32_t a2 = (uint32_t)__shfl((int)pk[2 * ks][0], srcB);
            uint32_t b2 = (uint32_t)__shfl((int)pk[2 * ks + 1][0], srcB);
            uint32_t a3 = (uint32_t)__shfl((int)pk[2 * ks][1], srcB);
            uint32_t b3 = (uint32_t)__shfl((int)pk[2 * ks + 1][1], srcB);
            bf16x8 pf = mk_frag(lo ? a0 : b0, lo ? a1 : b1, lo ? a2 : b2, lo ? a3 : b3);
            #pragma unroll
            for (int dg = 0; dg < 4; dg++) {
                int dr = dg * 16 + q16;
                bf16x8 vf = *(const bf16x8*)((char*)Vlds + dr * 128 + ((ks * 64 + hh * 16) ^ ((dr & 7) << 4)));
                acc[dg] = __builtin_amdgcn_mfma_f32_16x16x32_bf16(vf, pf, acc[dg], 0, 0, 0);
            }
        }
        __syncthreads();
    }

    lsum += __shfl_xor(lsum, 16);
    lsum += __shfl_xor(lsum, 32);

    {
        int r = tid >> 2, c4 = tid & 3;
        const float* src = Wrv + r * 129 + c4 * 32;
        #pragma unroll
        for (int i = 0; i < 4; i++) {
            float4 f0 = *(const float4*)(src + i * 8);
            float4 f1 = *(const float4*)(src + i * 8 + 4);
            uint4 pkv;
            pkv.x = pk_bf16(f0.x, f0.y);
            pkv.y = pk_bf16(f0.z, f0.w);
            pkv.z = pk_bf16(f1.x, f1.y);
            pkv.w = pk_bf16(f1.z, f1.w);
            *(uint4*)(smem + r * 256 + ((c4 * 64 + i * 16) ^ ((r & 7) << 4))) = pkv;
        }
    }
    __syncthreads();

    #pragma unroll 1
    for (int ks = 0; ks < 4; ks++) {
        uint4 raw = *(const uint4*)((char*)sband + ql * 272 + ks * 64 + hh * 16);
        uint32_t rr[4] = { raw.x, raw.y, raw.z, raw.w };
        uint32_t eu[4];
        #pragma unroll
        for (int i = 0; i < 4; i++) {
            float e0 = exp2_hw(bf2f((uint16_t)(rr[i] & 0xffff)) - MOFF);
            float e1 = exp2_hw(bf2f((uint16_t)(rr[i] >> 16)) - MOFF);
            eu[i] = pk_bf16(e0, e1);
        }
        bf16x8 ef = mk_frag(eu[0], eu[1], eu[2], eu[3]);
        #pragma unroll
        for (int dg = 0; dg < 4; dg++) {
            int dr = dg * 16 + q16;
            bf16x8 wf = *(const bf16x8*)(smem + dr * 256 + ((ks * 64 + hh * 16) ^ ((dr & 7) << 4)));
            acc[dg] = __builtin_amdgcn_mfma_f32_16x16x32_bf16(wf, ef, acc[dg], 0, 0, 0);
        }
    }
    {
        float e128 = exp2_hw(bf2f(sband[ql][128]) - MOFF);
        #pragma unroll
        for (int dg = 0; dg < 4; dg++)
            #pragma unroll
            for (int r = 0; r < 4; r++)
                acc[dg][r] += e128 * Wrv[(dg * 16 + 4 * hh + r) * 129 + 128];
    }

    float inv_l = 1.0f / lsum;
    #pragma unroll
    for (int dg = 0; dg < 4; dg++) {
        fx4 o4 = acc[dg] * inv_l;
        int d0 = dg * 16 + 4 * hh;
        *(fx4*)(out + (size_t)(b * SS + qglob) * (NH * DHH) + h * DHH + d0) = o4;
    }
}

// ---------------------------------------------------------------- launch
extern "C" void kernel_launch(void* const* d_in, const int* in_sizes, int n_in,
                              void* d_out, int out_size, void* d_ws, size_t ws_size,
                              hipStream_t stream) {
    const float* hs    = (const float*)d_in[0];
    const float* amask = (const float*)d_in[1];
    const float* Wq    = (const float*)d_in[2];
    const float* bq    = (const float*)d_in[3];
    const float* Wk    = (const float*)d_in[4];
    const float* bk    = (const float*)d_in[5];
    const float* Wv    = (const float*)d_in[6];
    const float* bv    = (const float*)d_in[7];
    const float* Wrk   = (const float*)d_in[8];
    const float* Wrv   = (const float*)d_in[9];
    float* out = (float*)d_out;

    char* ws = (char*)d_ws;
    uint16_t* qw   = (uint16_t*)(ws + (0ull  << 20));  // 8 MB  [bh][s][d]
    uint16_t* kw   = (uint16_t*)(ws + (8ull  << 20));  // 8 MB  [bh][s][d]
    uint16_t* vtw  = (uint16_t*)(ws + (16ull << 20));  // 8 MB  [bh][d][s]
    uint16_t* Wrkb = (uint16_t*)(ws + (24ull << 20));  // 16.5 KB bf16 Wrk

    cvt_kernel<<<9, 256, 0, stream>>>(Wrk, Wrkb, 129 * 64);

    proj_gemm3<<<dim3(32, 8, 3), 256, 0, stream>>>(hs, Wq, Wk, Wv, bq, bk, bv, qw, kw, vtw);

    attn_kernel<<<dim3(16, 64), 256, 0, stream>>>(qw, kw, vtw, amask, Wrkb, Wrv, out);
}

// Round 13
// 104.585 us; speedup vs baseline: 1.9109x; 1.9109x over previous
//
#include <hip/hip_runtime.h>
#include <stdint.h>

// Problem constants
#define BB 4
#define SS 1024
#define HIDD 1024
#define NH 16
#define DHH 64

#define LOG2E 1.44269504f
#define MOFF  28.8539008f   // 20 * log2(e)

typedef __attribute__((ext_vector_type(8))) short bf16x8;
typedef __attribute__((ext_vector_type(4))) float fx4;
typedef __attribute__((ext_vector_type(4))) int ix4;

__device__ __forceinline__ float bf2f(uint16_t u) {
    union { uint32_t u; float f; } x; x.u = ((uint32_t)u) << 16; return x.f;
}
__device__ __forceinline__ uint16_t f2bf(float f) {   // RNE
    uint32_t u = __builtin_bit_cast(uint32_t, f);
    u = u + 0x7fffu + ((u >> 16) & 1u);
    return (uint16_t)(u >> 16);
}
__device__ __forceinline__ uint32_t pk_bf16(float lo, float hi) {
    uint32_t r;
    asm volatile("v_cvt_pk_bf16_f32 %0, %1, %2" : "=v"(r) : "v"(lo), "v"(hi));
    return r;
}
__device__ __forceinline__ float exp2_hw(float x) {   // 2^x, single VALU op
    float r;
    asm("v_exp_f32 %0, %1" : "=v"(r) : "v"(x));
    return r;
}
__device__ __forceinline__ bf16x8 mk_frag(uint32_t u0, uint32_t u1, uint32_t u2, uint32_t u3) {
    ix4 v = { (int)u0, (int)u1, (int)u2, (int)u3 };
    return __builtin_bit_cast(bf16x8, v);
}

// ---------------------------------------------------------------- merged cvt f32->bf16
// regions: X 4M | Wq 1M | Wk 1M | Wv 1M | Wrk 8256   (r8-verified verbatim)
__global__ __launch_bounds__(256) void cvt_all(const float* __restrict__ x,
                                               const float* __restrict__ wq,
                                               const float* __restrict__ wk,
                                               const float* __restrict__ wv,
                                               const float* __restrict__ wrk,
                                               uint16_t* __restrict__ xb,
                                               uint16_t* __restrict__ wqb,
                                               uint16_t* __restrict__ wkb,
                                               uint16_t* __restrict__ wvb,
                                               uint16_t* __restrict__ wrkb) {
    long i = ((long)blockIdx.x * 256 + threadIdx.x) * 4;
    const float* in; uint16_t* out; long off;
    if (i < 4194304)      { in = x;   out = xb;   off = i; }
    else if (i < 5242880) { in = wq;  out = wqb;  off = i - 4194304; }
    else if (i < 6291456) { in = wk;  out = wkb;  off = i - 5242880; }
    else if (i < 7340032) { in = wv;  out = wvb;  off = i - 6291456; }
    else if (i < 7348288) { in = wrk; out = wrkb; off = i - 7340032; }
    else return;
    float4 v = *(const float4*)(in + off);
    uint2 p;
    p.x = pk_bf16(v.x, v.y);
    p.y = pk_bf16(v.z, v.w);
    *(uint2*)(out + off) = p;
}

// ---------------------------------------------------------------- projection GEMM (3 in one launch)
// r8-verified serial bf16 staging. ONLY change: bijective block permutation so
// each XCD gets 96 consecutive (z,n0,m0) tiles -> W/X panel reuse in its L2.
// Pure reordering of which block computes which tile; zero semantic content.
__global__ __launch_bounds__(256) void proj_gemm3(const uint16_t* __restrict__ X,
                                                  const uint16_t* __restrict__ Wq,
                                                  const uint16_t* __restrict__ Wk,
                                                  const uint16_t* __restrict__ Wv,
                                                  const float* __restrict__ bq,
                                                  const float* __restrict__ bk,
                                                  const float* __restrict__ bv,
                                                  uint16_t* __restrict__ oq,
                                                  uint16_t* __restrict__ ok,
                                                  uint16_t* __restrict__ ov) {
    // linear dispatch id (x fastest), remapped: XCD (lin&7) gets chunk (lin>>3)
    const int lin = (blockIdx.z * 8 + blockIdx.y) * 32 + blockIdx.x;   // [0,768)
    const int swz = (lin & 7) * 96 + (lin >> 3);                        // bijective
    const int z   = swz >> 8;          // 256 tiles per matrix
    const int rem = swz & 255;
    const int m0 = (rem & 31) * 128;
    const int n0 = (rem >> 5) * 128;

    const uint16_t* W = (z == 0) ? Wq : (z == 1) ? Wk : Wv;
    const float* bias = (z == 0) ? bq : (z == 1) ? bk : bv;
    uint16_t* out = (z == 0) ? oq : (z == 1) ? ok : ov;
    const float scl = (z == 0) ? LOG2E : 1.0f;

    __shared__ uint16_t Alds[128 * 64];  // [row m][k], XOR-swizzled ^((m&7)<<4)
    __shared__ uint16_t Blds[128 * 64];  // [row n][k]
    const int tid = threadIdx.x;
    const int lane = tid & 63;
    const int wvi = tid >> 6;
    const int q16 = lane & 15;
    const int hh = lane >> 4;
    const int wr = wvi >> 1, wc = wvi & 1;

    fx4 zero4 = { 0.f, 0.f, 0.f, 0.f };
    fx4 acc[4][4];
    #pragma unroll
    for (int a = 0; a < 4; a++)
        #pragma unroll
        for (int c = 0; c < 4; c++) acc[a][c] = zero4;

    const int srow = tid >> 1, shalf = tid & 1;
    for (int k0 = 0; k0 < HIDD; k0 += 64) {
        // reg-staged: 64B per thread for A and B (serial; no cross-iter prefetch)
        const uint16_t* gA = X + (size_t)(m0 + srow) * HIDD + k0 + shalf * 32;
        const uint16_t* gB = W + (size_t)(n0 + srow) * HIDD + k0 + shalf * 32;
        #pragma unroll
        for (int i = 0; i < 4; i++) {
            uint4 va = *(const uint4*)(gA + i * 8);
            uint4 vb = *(const uint4*)(gB + i * 8);
            uint32_t bo = (uint32_t)((shalf * 64 + i * 16) ^ ((srow & 7) << 4));
            *(uint4*)((char*)Alds + srow * 128 + bo) = va;
            *(uint4*)((char*)Blds + srow * 128 + bo) = vb;
        }
        __syncthreads();
        #pragma unroll
        for (int kk = 0; kk < 2; kk++) {
            bf16x8 af[4], bfr[4];
            #pragma unroll
            for (int mi = 0; mi < 4; mi++) {
                int mr = wr * 64 + mi * 16 + q16;
                af[mi] = *(const bf16x8*)((char*)Alds + mr * 128 + ((kk * 64 + hh * 16) ^ ((mr & 7) << 4)));
            }
            #pragma unroll
            for (int ni = 0; ni < 4; ni++) {
                int nr = wc * 64 + ni * 16 + q16;
                bfr[ni] = *(const bf16x8*)((char*)Blds + nr * 128 + ((kk * 64 + hh * 16) ^ ((nr & 7) << 4)));
            }
            #pragma unroll
            for (int mi = 0; mi < 4; mi++)
                #pragma unroll
                for (int ni = 0; ni < 4; ni++)
                    acc[mi][ni] = __builtin_amdgcn_mfma_f32_16x16x32_bf16(af[mi], bfr[ni], acc[mi][ni], 0, 0, 0);
        }
        __syncthreads();
    }

    if (z < 2) {
        // epilogue: C[m, n] -> out[b][h][s][d], bf16 (Q prescaled)
        #pragma unroll
        for (int ni = 0; ni < 4; ni++) {
            int n = n0 + wc * 64 + ni * 16 + q16;
            float bvv = bias[n];
            int h = n >> 6, d = n & 63;
            #pragma unroll
            for (int mi = 0; mi < 4; mi++) {
                #pragma unroll
                for (int r = 0; r < 4; r++) {
                    int m = m0 + wr * 64 + mi * 16 + 4 * hh + r;
                    int b = m >> 10, s = m & 1023;
                    out[(size_t)b * (NH * SS * DHH) + (size_t)h * (SS * DHH) + s * DHH + d] =
                        f2bf((acc[mi][ni][r] + bvv) * scl);
                }
            }
        }
    } else {
        // epilogue: C[m, n] -> V^T [bh][d][s]; r-values are s-consecutive -> uint2
        int b = m0 >> 10;                      // blocks never straddle a batch (128 | 1024)
        int sbase = (m0 & 1023) + wr * 64;
        #pragma unroll
        for (int ni = 0; ni < 4; ni++) {
            int n = n0 + wc * 64 + ni * 16 + q16;
            float bvv = bias[n];
            int h = n >> 6, d = n & 63;
            uint16_t* base = out + ((size_t)(b * 16 + h) * 64 + d) * SS + sbase;
            #pragma unroll
            for (int mi = 0; mi < 4; mi++) {
                uint2 pp;
                pp.x = pk_bf16(acc[mi][ni][0] + bvv, acc[mi][ni][1] + bvv);
                pp.y = pk_bf16(acc[mi][ni][2] + bvv, acc[mi][ni][3] + bvv);
                *(uint2*)(base + mi * 16 + 4 * hh) = pp;
            }
        }
    }
}

// ---------------------------------------------------------------- fused attention
// BYTE-IDENTICAL to the round-8 verified kernel (116.1 µs, absmax 0.043).
__global__ __launch_bounds__(256) void attn_kernel(
    const uint16_t* __restrict__ qg,   // [BH][S][64]  (prescaled by log2e)
    const uint16_t* __restrict__ kg,   // [BH][S][64]
    const uint16_t* __restrict__ vtg,  // [BH][64][S]
    const float* __restrict__ amask,   // [B][S]
    const uint16_t* __restrict__ Wrkb, // [129][64] bf16
    const float* __restrict__ Wrv,     // [64][129]
    float* __restrict__ out)           // [B][S][NH*64]
{
    __shared__ __align__(16) char smem[37888];
    uint16_t* Klds = (uint16_t*)smem;                           // [64][64] swz, 8192 B
    uint16_t* Vlds = (uint16_t*)(smem + 8192);                  // [64][64] swz, 8192 B
    uint16_t (*sband)[136] = (uint16_t (*)[136])(smem + 16384); // 17408 B
    float* maskf = (float*)(smem + 33792);                      // 4096 B f32 prescaled bias

    const int tid = threadIdx.x;
    const int lane = tid & 63;
    const int wv = tid >> 6;
    const int q16 = lane & 15;
    const int hh = lane >> 4;
    const int id = blockIdx.y * 16 + blockIdx.x;
    const int xcd = id & 7, slot = id >> 3;
    const int bh = xcd + 8 * (slot >> 4);
    const int qt = slot & 15;
    const int b = bh >> 4;
    const int h = bh & 15;
    const int q0 = qt * 64;
    const int ql = wv * 16 + q16;
    const int qglob = q0 + ql;

    const uint16_t* qbh = qg + (size_t)bh * (SS * 64);
    const uint16_t* kbh = kg + (size_t)bh * (SS * 64);
    const uint16_t* vbh = vtg + (size_t)bh * (64 * SS);

    bf16x8 qf[2];
    #pragma unroll
    for (int ks = 0; ks < 2; ks++)
        qf[ks] = *(const bf16x8*)(qbh + (size_t)qglob * 64 + ks * 32 + hh * 8);

    const int srow = tid >> 2, spart = tid & 3;
    const uint32_t sb0 = (uint32_t)((spart * 32) ^ ((srow & 7) << 4));
    const uint32_t sb1 = (uint32_t)((spart * 32 + 16) ^ ((srow & 7) << 4));
    const uint16_t* gk0 = kbh + (size_t)srow * 64 + spart * 16;
    const uint16_t* gv0 = vbh + (size_t)srow * SS + spart * 16;
    uint4 ka  = *(const uint4*)gk0;
    uint4 kb2 = *(const uint4*)(gk0 + 8);
    uint4 va  = *(const uint4*)gv0;
    uint4 vb2 = *(const uint4*)(gv0 + 8);

    for (int i = tid * 4; i < SS; i += 1024) {
        float4 mv = *(const float4*)(amask + b * SS + i);
        fx4 o;
        o[0] = (1.0f - mv.x) * -2.0e38f - MOFF;
        o[1] = (1.0f - mv.y) * -2.0e38f - MOFF;
        o[2] = (1.0f - mv.z) * -2.0e38f - MOFF;
        o[3] = (1.0f - mv.w) * -2.0e38f - MOFF;
        *(fx4*)&maskf[i] = o;
    }

    #pragma unroll 1
    for (int wg = 0; wg < 9; wg++) {
        fx4 a = { 0.f, 0.f, 0.f, 0.f };
        int wrow = wg * 16 + q16; if (wrow > 128) wrow = 128;
        #pragma unroll
        for (int ks = 0; ks < 2; ks++) {
            bf16x8 af = *(const bf16x8*)(Wrkb + wrow * 64 + ks * 32 + hh * 8);
            a = __builtin_amdgcn_mfma_f32_16x16x32_bf16(af, qf[ks], a, 0, 0, 0);
        }
        if (wg < 8) {
            uint2 pp;
            pp.x = pk_bf16(a[0], a[1]);
            pp.y = pk_bf16(a[2], a[3]);
            *(uint2*)&sband[ql][wg * 16 + 4 * hh] = pp;
        } else if (hh == 0) {
            sband[ql][128] = f2bf(a[0]);
        }
    }
    if (qt == 0 || qt == 15) {
        int oend = hh * 33 + 33; if (oend > 129) oend = 129;
        for (int o = hh * 33; o < oend; o++) {
            int col = qglob + o - 64;
            if (col < 0 || col >= SS) sband[ql][o] = 0xff7f;
        }
    }
    __syncthreads();

    float lsum = 0.f;
    fx4 acc[4];
    #pragma unroll
    for (int dg = 0; dg < 4; dg++) acc[dg] = fx4{ 0.f, 0.f, 0.f, 0.f };

    const int srcA = q16 + 16 * ((2 * hh) & 3);
    const int srcB = q16 + 16 * ((2 * hh + 1) & 3);
    const bool lo = (hh < 2);

    for (int jt = 0; jt < 16; jt++) {
        *(uint4*)((char*)Klds + srow * 128 + sb0) = ka;
        *(uint4*)((char*)Klds + srow * 128 + sb1) = kb2;
        *(uint4*)((char*)Vlds + srow * 128 + sb0) = va;
        *(uint4*)((char*)Vlds + srow * 128 + sb1) = vb2;
        __syncthreads();

        if (jt < 15) {
            ka  = *(const uint4*)(gk0 + (size_t)(jt + 1) * 4096);
            kb2 = *(const uint4*)(gk0 + (size_t)(jt + 1) * 4096 + 8);
            va  = *(const uint4*)(gv0 + (jt + 1) * 64);
            vb2 = *(const uint4*)(gv0 + (jt + 1) * 64 + 8);
        }

        const int dj = jt - qt;
        const bool band = (dj >= -1) && (dj <= 1);
        uint32_t pk[4][2];
        #pragma unroll
        for (int mg = 0; mg < 4; mg++) {
            int mr = mg * 16 + q16;
            bf16x8 kf0 = *(const bf16x8*)((char*)Klds + mr * 128 + ((hh * 16) ^ ((mr & 7) << 4)));
            bf16x8 kf1 = *(const bf16x8*)((char*)Klds + mr * 128 + ((64 + hh * 16) ^ ((mr & 7) << 4)));
            fx4 s4 = { 0.f, 0.f, 0.f, 0.f };
            s4 = __builtin_amdgcn_mfma_f32_16x16x32_bf16(kf0, qf[0], s4, 0, 0, 0);
            s4 = __builtin_amdgcn_mfma_f32_16x16x32_bf16(kf1, qf[1], s4, 0, 0, 0);
            int mb = jt * 64 + mg * 16 + 4 * hh;
            fx4 mk4 = *(const fx4*)&maskf[mb];
            float p[4];
            #pragma unroll
            for (int r = 0; r < 4; r++) {
                int m = mb + r;
                float s = s4[r] + mk4[r];
                int o = m - qglob + 64;
                bool inb = band && (o >= 0) && (o <= 128);
                if (inb) {
                    s += bf2f(sband[ql][o]);
                    sband[ql][o] = f2bf(s + MOFF);
                }
                p[r] = exp2_hw(s);
            }
            lsum += (p[0] + p[1]) + (p[2] + p[3]);
            pk[mg][0] = pk_bf16(p[0], p[1]);
            pk[mg][1] = pk_bf16(p[2], p[3]);
        }

        #pragma unroll
        for (int ks = 0; ks < 2; ks++) {
            uint32_t a0 = (uint32_t)__shfl((int)pk[2 * ks][0], srcA);
            uint32_t b0 = (uint32_t)__shfl((int)pk[2 * ks + 1][0], srcA);
            uint32_t a1 = (uint32_t)__shfl((int)pk[2 * ks][1], srcA);
            uint32_t b1 = (uint32_t)__shfl((int)pk[2 * ks + 1][1], srcA);
            uint32_t a2 = (uint32_t)__shfl((int)pk[2 * ks][0], srcB);
            uint32_t b2 = (uint32_t)__shfl((int)pk[2 * ks + 1][0], srcB);
            uint32_t a3 = (uint32_t)__shfl((int)pk[2 * ks][1], srcB);
            uint32_t b3 = (uint32_t)__shfl((int)pk[2 * ks + 1][1], srcB);
            bf16x8 pf = mk_frag(lo ? a0 : b0, lo ? a1 : b1, lo ? a2 : b2, lo ? a3 : b3);
            #pragma unroll
            for (int dg = 0; dg < 4; dg++) {
                int dr = dg * 16 + q16;
                bf16x8 vf = *(const bf16x8*)((char*)Vlds + dr * 128 + ((ks * 64 + hh * 16) ^ ((dr & 7) << 4)));
                acc[dg] = __builtin_amdgcn_mfma_f32_16x16x32_bf16(vf, pf, acc[dg], 0, 0, 0);
            }
        }
        __syncthreads();
    }

    lsum += __shfl_xor(lsum, 16);
    lsum += __shfl_xor(lsum, 32);

    {
        int r = tid >> 2, c4 = tid & 3;
        const float* src = Wrv + r * 129 + c4 * 32;
        #pragma unroll
        for (int i = 0; i < 4; i++) {
            float4 f0 = *(const float4*)(src + i * 8);
            float4 f1 = *(const float4*)(src + i * 8 + 4);
            uint4 pkv;
            pkv.x = pk_bf16(f0.x, f0.y);
            pkv.y = pk_bf16(f0.z, f0.w);
            pkv.z = pk_bf16(f1.x, f1.y);
            pkv.w = pk_bf16(f1.z, f1.w);
            *(uint4*)(smem + r * 256 + ((c4 * 64 + i * 16) ^ ((r & 7) << 4))) = pkv;
        }
    }
    __syncthreads();

    #pragma unroll 1
    for (int ks = 0; ks < 4; ks++) {
        uint4 raw = *(const uint4*)((char*)sband + ql * 272 + ks * 64 + hh * 16);
        uint32_t rr[4] = { raw.x, raw.y, raw.z, raw.w };
        uint32_t eu[4];
        #pragma unroll
        for (int i = 0; i < 4; i++) {
            float e0 = exp2_hw(bf2f((uint16_t)(rr[i] & 0xffff)) - MOFF);
            float e1 = exp2_hw(bf2f((uint16_t)(rr[i] >> 16)) - MOFF);
            eu[i] = pk_bf16(e0, e1);
        }
        bf16x8 ef = mk_frag(eu[0], eu[1], eu[2], eu[3]);
        #pragma unroll
        for (int dg = 0; dg < 4; dg++) {
            int dr = dg * 16 + q16;
            bf16x8 wf = *(const bf16x8*)(smem + dr * 256 + ((ks * 64 + hh * 16) ^ ((dr & 7) << 4)));
            acc[dg] = __builtin_amdgcn_mfma_f32_16x16x32_bf16(wf, ef, acc[dg], 0, 0, 0);
        }
    }
    {
        float e128 = exp2_hw(bf2f(sband[ql][128]) - MOFF);
        #pragma unroll
        for (int dg = 0; dg < 4; dg++)
            #pragma unroll
            for (int r = 0; r < 4; r++)
                acc[dg][r] += e128 * Wrv[(dg * 16 + 4 * hh + r) * 129 + 128];
    }

    float inv_l = 1.0f / lsum;
    #pragma unroll
    for (int dg = 0; dg < 4; dg++) {
        fx4 o4 = acc[dg] * inv_l;
        int d0 = dg * 16 + 4 * hh;
        *(fx4*)(out + (size_t)(b * SS + qglob) * (NH * DHH) + h * DHH + d0) = o4;
    }
}

// ---------------------------------------------------------------- launch
extern "C" void kernel_launch(void* const* d_in, const int* in_sizes, int n_in,
                              void* d_out, int out_size, void* d_ws, size_t ws_size,
                              hipStream_t stream) {
    const float* hs    = (const float*)d_in[0];
    const float* amask = (const float*)d_in[1];
    const float* Wq    = (const float*)d_in[2];
    const float* bq    = (const float*)d_in[3];
    const float* Wk    = (const float*)d_in[4];
    const float* bk    = (const float*)d_in[5];
    const float* Wv    = (const float*)d_in[6];
    const float* bv    = (const float*)d_in[7];
    const float* Wrk   = (const float*)d_in[8];
    const float* Wrv   = (const float*)d_in[9];
    float* out = (float*)d_out;

    char* ws = (char*)d_ws;
    uint16_t* Xb   = (uint16_t*)(ws + (0ull  << 20));  // 8 MB  bf16 X [4096][1024]
    uint16_t* Wqb  = (uint16_t*)(ws + (8ull  << 20));  // 2 MB
    uint16_t* Wkb  = (uint16_t*)(ws + (10ull << 20));  // 2 MB
    uint16_t* Wvb  = (uint16_t*)(ws + (12ull << 20));  // 2 MB
    uint16_t* qw   = (uint16_t*)(ws + (14ull << 20));  // 8 MB  [bh][s][d]
    uint16_t* kw   = (uint16_t*)(ws + (22ull << 20));  // 8 MB  [bh][s][d]
    uint16_t* vtw  = (uint16_t*)(ws + (38ull << 20));  // 8 MB  [bh][d][s]
    uint16_t* Wrkb = (uint16_t*)(ws + (46ull << 20));  // 16.5 KB bf16 Wrk

    cvt_all<<<7177, 256, 0, stream>>>(hs, Wq, Wk, Wv, Wrk, Xb, Wqb, Wkb, Wvb, Wrkb);

    proj_gemm3<<<dim3(32, 8, 3), 256, 0, stream>>>(Xb, Wqb, Wkb, Wvb, bq, bk, bv, qw, kw, vtw);

    attn_kernel<<<dim3(16, 64), 256, 0, stream>>>(qw, kw, vtw, amask, Wrkb, Wrv, out);
}

// Round 14
// 101.931 us; speedup vs baseline: 1.9606x; 1.0260x over previous
//
#include <hip/hip_runtime.h>
#include <stdint.h>

// Problem constants
#define BB 4
#define SS 1024
#define HIDD 1024
#define NH 16
#define DHH 64

#define LOG2E 1.44269504f
#define MOFF  28.8539008f   // 20 * log2(e)

typedef __attribute__((ext_vector_type(8))) short bf16x8;
typedef __attribute__((ext_vector_type(4))) float fx4;
typedef __attribute__((ext_vector_type(4))) int ix4;

__device__ __forceinline__ float bf2f(uint16_t u) {
    union { uint32_t u; float f; } x; x.u = ((uint32_t)u) << 16; return x.f;
}
__device__ __forceinline__ uint16_t f2bf(float f) {   // RNE
    uint32_t u = __builtin_bit_cast(uint32_t, f);
    u = u + 0x7fffu + ((u >> 16) & 1u);
    return (uint16_t)(u >> 16);
}
__device__ __forceinline__ uint32_t pk_bf16(float lo, float hi) {
    uint32_t r;
    asm volatile("v_cvt_pk_bf16_f32 %0, %1, %2" : "=v"(r) : "v"(lo), "v"(hi));
    return r;
}
__device__ __forceinline__ float exp2_hw(float x) {   // 2^x, single VALU op
    float r;
    asm("v_exp_f32 %0, %1" : "=v"(r) : "v"(x));
    return r;
}
__device__ __forceinline__ bf16x8 mk_frag(uint32_t u0, uint32_t u1, uint32_t u2, uint32_t u3) {
    ix4 v = { (int)u0, (int)u1, (int)u2, (int)u3 };
    return __builtin_bit_cast(bf16x8, v);
}

// ---------------------------------------------------------------- merged cvt f32->bf16
// regions: X 4M | Wq 1M | Wk 1M | Wv 1M | Wrk 8256   (r8-verified verbatim)
__global__ __launch_bounds__(256) void cvt_all(const float* __restrict__ x,
                                               const float* __restrict__ wq,
                                               const float* __restrict__ wk,
                                               const float* __restrict__ wv,
                                               const float* __restrict__ wrk,
                                               uint16_t* __restrict__ xb,
                                               uint16_t* __restrict__ wqb,
                                               uint16_t* __restrict__ wkb,
                                               uint16_t* __restrict__ wvb,
                                               uint16_t* __restrict__ wrkb) {
    long i = ((long)blockIdx.x * 256 + threadIdx.x) * 4;
    const float* in; uint16_t* out; long off;
    if (i < 4194304)      { in = x;   out = xb;   off = i; }
    else if (i < 5242880) { in = wq;  out = wqb;  off = i - 4194304; }
    else if (i < 6291456) { in = wk;  out = wkb;  off = i - 5242880; }
    else if (i < 7340032) { in = wv;  out = wvb;  off = i - 6291456; }
    else if (i < 7348288) { in = wrk; out = wrkb; off = i - 7340032; }
    else return;
    float4 v = *(const float4*)(in + off);
    uint2 p;
    p.x = pk_bf16(v.x, v.y);
    p.y = pk_bf16(v.z, v.w);
    *(uint2*)(out + off) = p;
}

// ---------------------------------------------------------------- projection GEMM (3 in one launch)
// r13-verified: serial bf16 staging + bijective XCD block permutation.
__global__ __launch_bounds__(256) void proj_gemm3(const uint16_t* __restrict__ X,
                                                  const uint16_t* __restrict__ Wq,
                                                  const uint16_t* __restrict__ Wk,
                                                  const uint16_t* __restrict__ Wv,
                                                  const float* __restrict__ bq,
                                                  const float* __restrict__ bk,
                                                  const float* __restrict__ bv,
                                                  uint16_t* __restrict__ oq,
                                                  uint16_t* __restrict__ ok,
                                                  uint16_t* __restrict__ ov) {
    // linear dispatch id (x fastest), remapped: XCD (lin&7) gets chunk (lin>>3)
    const int lin = (blockIdx.z * 8 + blockIdx.y) * 32 + blockIdx.x;   // [0,768)
    const int swz = (lin & 7) * 96 + (lin >> 3);                        // bijective
    const int z   = swz >> 8;          // 256 tiles per matrix
    const int rem = swz & 255;
    const int m0 = (rem & 31) * 128;
    const int n0 = (rem >> 5) * 128;

    const uint16_t* W = (z == 0) ? Wq : (z == 1) ? Wk : Wv;
    const float* bias = (z == 0) ? bq : (z == 1) ? bk : bv;
    uint16_t* out = (z == 0) ? oq : (z == 1) ? ok : ov;
    const float scl = (z == 0) ? LOG2E : 1.0f;

    __shared__ uint16_t Alds[128 * 64];  // [row m][k], XOR-swizzled ^((m&7)<<4)
    __shared__ uint16_t Blds[128 * 64];  // [row n][k]
    const int tid = threadIdx.x;
    const int lane = tid & 63;
    const int wvi = tid >> 6;
    const int q16 = lane & 15;
    const int hh = lane >> 4;
    const int wr = wvi >> 1, wc = wvi & 1;

    fx4 zero4 = { 0.f, 0.f, 0.f, 0.f };
    fx4 acc[4][4];
    #pragma unroll
    for (int a = 0; a < 4; a++)
        #pragma unroll
        for (int c = 0; c < 4; c++) acc[a][c] = zero4;

    const int srow = tid >> 1, shalf = tid & 1;
    for (int k0 = 0; k0 < HIDD; k0 += 64) {
        // reg-staged: 64B per thread for A and B (serial; no cross-iter prefetch)
        const uint16_t* gA = X + (size_t)(m0 + srow) * HIDD + k0 + shalf * 32;
        const uint16_t* gB = W + (size_t)(n0 + srow) * HIDD + k0 + shalf * 32;
        #pragma unroll
        for (int i = 0; i < 4; i++) {
            uint4 va = *(const uint4*)(gA + i * 8);
            uint4 vb = *(const uint4*)(gB + i * 8);
            uint32_t bo = (uint32_t)((shalf * 64 + i * 16) ^ ((srow & 7) << 4));
            *(uint4*)((char*)Alds + srow * 128 + bo) = va;
            *(uint4*)((char*)Blds + srow * 128 + bo) = vb;
        }
        __syncthreads();
        #pragma unroll
        for (int kk = 0; kk < 2; kk++) {
            bf16x8 af[4], bfr[4];
            #pragma unroll
            for (int mi = 0; mi < 4; mi++) {
                int mr = wr * 64 + mi * 16 + q16;
                af[mi] = *(const bf16x8*)((char*)Alds + mr * 128 + ((kk * 64 + hh * 16) ^ ((mr & 7) << 4)));
            }
            #pragma unroll
            for (int ni = 0; ni < 4; ni++) {
                int nr = wc * 64 + ni * 16 + q16;
                bfr[ni] = *(const bf16x8*)((char*)Blds + nr * 128 + ((kk * 64 + hh * 16) ^ ((nr & 7) << 4)));
            }
            #pragma unroll
            for (int mi = 0; mi < 4; mi++)
                #pragma unroll
                for (int ni = 0; ni < 4; ni++)
                    acc[mi][ni] = __builtin_amdgcn_mfma_f32_16x16x32_bf16(af[mi], bfr[ni], acc[mi][ni], 0, 0, 0);
        }
        __syncthreads();
    }

    if (z < 2) {
        // epilogue: C[m, n] -> out[b][h][s][d], bf16 (Q prescaled)
        #pragma unroll
        for (int ni = 0; ni < 4; ni++) {
            int n = n0 + wc * 64 + ni * 16 + q16;
            float bvv = bias[n];
            int h = n >> 6, d = n & 63;
            #pragma unroll
            for (int mi = 0; mi < 4; mi++) {
                #pragma unroll
                for (int r = 0; r < 4; r++) {
                    int m = m0 + wr * 64 + mi * 16 + 4 * hh + r;
                    int b = m >> 10, s = m & 1023;
                    out[(size_t)b * (NH * SS * DHH) + (size_t)h * (SS * DHH) + s * DHH + d] =
                        f2bf((acc[mi][ni][r] + bvv) * scl);
                }
            }
        }
    } else {
        // epilogue: C[m, n] -> V^T [bh][d][s]; r-values are s-consecutive -> uint2
        int b = m0 >> 10;                      // blocks never straddle a batch (128 | 1024)
        int sbase = (m0 & 1023) + wr * 64;
        #pragma unroll
        for (int ni = 0; ni < 4; ni++) {
            int n = n0 + wc * 64 + ni * 16 + q16;
            float bvv = bias[n];
            int h = n >> 6, d = n & 63;
            uint16_t* base = out + ((size_t)(b * 16 + h) * 64 + d) * SS + sbase;
            #pragma unroll
            for (int mi = 0; mi < 4; mi++) {
                uint2 pp;
                pp.x = pk_bf16(acc[mi][ni][0] + bvv, acc[mi][ni][1] + bvv);
                pp.y = pk_bf16(acc[mi][ni][2] + bvv, acc[mi][ni][3] + bvv);
                *(uint2*)(base + mi * 16 + 4 * hh) = pp;
            }
        }
    }
}

// ---------------------------------------------------------------- fused attention
// r8-verified kernel + ONE change: the mg loop is split on the wave-uniform
// `band` flag. Band path = exact r8 body; lean path = identical arithmetic with
// inb constant-folded false (13/16 iterations skip all sband address math).
__global__ __launch_bounds__(256) void attn_kernel(
    const uint16_t* __restrict__ qg,   // [BH][S][64]  (prescaled by log2e)
    const uint16_t* __restrict__ kg,   // [BH][S][64]
    const uint16_t* __restrict__ vtg,  // [BH][64][S]
    const float* __restrict__ amask,   // [B][S]
    const uint16_t* __restrict__ Wrkb, // [129][64] bf16
    const float* __restrict__ Wrv,     // [64][129]
    float* __restrict__ out)           // [B][S][NH*64]
{
    __shared__ __align__(16) char smem[37888];
    uint16_t* Klds = (uint16_t*)smem;                           // [64][64] swz, 8192 B
    uint16_t* Vlds = (uint16_t*)(smem + 8192);                  // [64][64] swz, 8192 B
    uint16_t (*sband)[136] = (uint16_t (*)[136])(smem + 16384); // 17408 B
    float* maskf = (float*)(smem + 33792);                      // 4096 B f32 prescaled bias

    const int tid = threadIdx.x;
    const int lane = tid & 63;
    const int wv = tid >> 6;
    const int q16 = lane & 15;
    const int hh = lane >> 4;
    const int id = blockIdx.y * 16 + blockIdx.x;
    const int xcd = id & 7, slot = id >> 3;
    const int bh = xcd + 8 * (slot >> 4);
    const int qt = slot & 15;
    const int b = bh >> 4;
    const int h = bh & 15;
    const int q0 = qt * 64;
    const int ql = wv * 16 + q16;
    const int qglob = q0 + ql;

    const uint16_t* qbh = qg + (size_t)bh * (SS * 64);
    const uint16_t* kbh = kg + (size_t)bh * (SS * 64);
    const uint16_t* vbh = vtg + (size_t)bh * (64 * SS);

    bf16x8 qf[2];
    #pragma unroll
    for (int ks = 0; ks < 2; ks++)
        qf[ks] = *(const bf16x8*)(qbh + (size_t)qglob * 64 + ks * 32 + hh * 8);

    const int srow = tid >> 2, spart = tid & 3;
    const uint32_t sb0 = (uint32_t)((spart * 32) ^ ((srow & 7) << 4));
    const uint32_t sb1 = (uint32_t)((spart * 32 + 16) ^ ((srow & 7) << 4));
    const uint16_t* gk0 = kbh + (size_t)srow * 64 + spart * 16;
    const uint16_t* gv0 = vbh + (size_t)srow * SS + spart * 16;
    uint4 ka  = *(const uint4*)gk0;
    uint4 kb2 = *(const uint4*)(gk0 + 8);
    uint4 va  = *(const uint4*)gv0;
    uint4 vb2 = *(const uint4*)(gv0 + 8);

    for (int i = tid * 4; i < SS; i += 1024) {
        float4 mv = *(const float4*)(amask + b * SS + i);
        fx4 o;
        o[0] = (1.0f - mv.x) * -2.0e38f - MOFF;
        o[1] = (1.0f - mv.y) * -2.0e38f - MOFF;
        o[2] = (1.0f - mv.z) * -2.0e38f - MOFF;
        o[3] = (1.0f - mv.w) * -2.0e38f - MOFF;
        *(fx4*)&maskf[i] = o;
    }

    #pragma unroll 1
    for (int wg = 0; wg < 9; wg++) {
        fx4 a = { 0.f, 0.f, 0.f, 0.f };
        int wrow = wg * 16 + q16; if (wrow > 128) wrow = 128;
        #pragma unroll
        for (int ks = 0; ks < 2; ks++) {
            bf16x8 af = *(const bf16x8*)(Wrkb + wrow * 64 + ks * 32 + hh * 8);
            a = __builtin_amdgcn_mfma_f32_16x16x32_bf16(af, qf[ks], a, 0, 0, 0);
        }
        if (wg < 8) {
            uint2 pp;
            pp.x = pk_bf16(a[0], a[1]);
            pp.y = pk_bf16(a[2], a[3]);
            *(uint2*)&sband[ql][wg * 16 + 4 * hh] = pp;
        } else if (hh == 0) {
            sband[ql][128] = f2bf(a[0]);
        }
    }
    if (qt == 0 || qt == 15) {
        int oend = hh * 33 + 33; if (oend > 129) oend = 129;
        for (int o = hh * 33; o < oend; o++) {
            int col = qglob + o - 64;
            if (col < 0 || col >= SS) sband[ql][o] = 0xff7f;
        }
    }
    __syncthreads();

    float lsum = 0.f;
    fx4 acc[4];
    #pragma unroll
    for (int dg = 0; dg < 4; dg++) acc[dg] = fx4{ 0.f, 0.f, 0.f, 0.f };

    const int srcA = q16 + 16 * ((2 * hh) & 3);
    const int srcB = q16 + 16 * ((2 * hh + 1) & 3);
    const bool lo = (hh < 2);

    for (int jt = 0; jt < 16; jt++) {
        *(uint4*)((char*)Klds + srow * 128 + sb0) = ka;
        *(uint4*)((char*)Klds + srow * 128 + sb1) = kb2;
        *(uint4*)((char*)Vlds + srow * 128 + sb0) = va;
        *(uint4*)((char*)Vlds + srow * 128 + sb1) = vb2;
        __syncthreads();

        if (jt < 15) {
            ka  = *(const uint4*)(gk0 + (size_t)(jt + 1) * 4096);
            kb2 = *(const uint4*)(gk0 + (size_t)(jt + 1) * 4096 + 8);
            va  = *(const uint4*)(gv0 + (jt + 1) * 64);
            vb2 = *(const uint4*)(gv0 + (jt + 1) * 64 + 8);
        }

        const int dj = jt - qt;
        const bool band = (dj >= -1) && (dj <= 1);
        uint32_t pk[4][2];
        if (band) {
            // ---- band path: exact r8 body (bias read-modify-write + exp)
            #pragma unroll
            for (int mg = 0; mg < 4; mg++) {
                int mr = mg * 16 + q16;
                bf16x8 kf0 = *(const bf16x8*)((char*)Klds + mr * 128 + ((hh * 16) ^ ((mr & 7) << 4)));
                bf16x8 kf1 = *(const bf16x8*)((char*)Klds + mr * 128 + ((64 + hh * 16) ^ ((mr & 7) << 4)));
                fx4 s4 = { 0.f, 0.f, 0.f, 0.f };
                s4 = __builtin_amdgcn_mfma_f32_16x16x32_bf16(kf0, qf[0], s4, 0, 0, 0);
                s4 = __builtin_amdgcn_mfma_f32_16x16x32_bf16(kf1, qf[1], s4, 0, 0, 0);
                int mb = jt * 64 + mg * 16 + 4 * hh;
                fx4 mk4 = *(const fx4*)&maskf[mb];
                float p[4];
                #pragma unroll
                for (int r = 0; r < 4; r++) {
                    int m = mb + r;
                    float s = s4[r] + mk4[r];
                    int o = m - qglob + 64;
                    bool inb = (o >= 0) && (o <= 128);
                    if (inb) {
                        s += bf2f(sband[ql][o]);
                        sband[ql][o] = f2bf(s + MOFF);
                    }
                    p[r] = exp2_hw(s);
                }
                lsum += (p[0] + p[1]) + (p[2] + p[3]);
                pk[mg][0] = pk_bf16(p[0], p[1]);
                pk[mg][1] = pk_bf16(p[2], p[3]);
            }
        } else {
            // ---- lean path: identical arithmetic with inb==false folded out
            #pragma unroll
            for (int mg = 0; mg < 4; mg++) {
                int mr = mg * 16 + q16;
                bf16x8 kf0 = *(const bf16x8*)((char*)Klds + mr * 128 + ((hh * 16) ^ ((mr & 7) << 4)));
                bf16x8 kf1 = *(const bf16x8*)((char*)Klds + mr * 128 + ((64 + hh * 16) ^ ((mr & 7) << 4)));
                fx4 s4 = { 0.f, 0.f, 0.f, 0.f };
                s4 = __builtin_amdgcn_mfma_f32_16x16x32_bf16(kf0, qf[0], s4, 0, 0, 0);
                s4 = __builtin_amdgcn_mfma_f32_16x16x32_bf16(kf1, qf[1], s4, 0, 0, 0);
                int mb = jt * 64 + mg * 16 + 4 * hh;
                fx4 mk4 = *(const fx4*)&maskf[mb];
                float p[4];
                #pragma unroll
                for (int r = 0; r < 4; r++)
                    p[r] = exp2_hw(s4[r] + mk4[r]);
                lsum += (p[0] + p[1]) + (p[2] + p[3]);
                pk[mg][0] = pk_bf16(p[0], p[1]);
                pk[mg][1] = pk_bf16(p[2], p[3]);
            }
        }

        #pragma unroll
        for (int ks = 0; ks < 2; ks++) {
            uint32_t a0 = (uint32_t)__shfl((int)pk[2 * ks][0], srcA);
            uint32_t b0 = (uint32_t)__shfl((int)pk[2 * ks + 1][0], srcA);
            uint32_t a1 = (uint32_t)__shfl((int)pk[2 * ks][1], srcA);
            uint32_t b1 = (uint32_t)__shfl((int)pk[2 * ks + 1][1], srcA);
            uint32_t a2 = (uint32_t)__shfl((int)pk[2 * ks][0], srcB);
            uint32_t b2 = (uint32_t)__shfl((int)pk[2 * ks + 1][0], srcB);
            uint32_t a3 = (uint32_t)__shfl((int)pk[2 * ks][1], srcB);
            uint32_t b3 = (uint32_t)__shfl((int)pk[2 * ks + 1][1], srcB);
            bf16x8 pf = mk_frag(lo ? a0 : b0, lo ? a1 : b1, lo ? a2 : b2, lo ? a3 : b3);
            #pragma unroll
            for (int dg = 0; dg < 4; dg++) {
                int dr = dg * 16 + q16;
                bf16x8 vf = *(const bf16x8*)((char*)Vlds + dr * 128 + ((ks * 64 + hh * 16) ^ ((dr & 7) << 4)));
                acc[dg] = __builtin_amdgcn_mfma_f32_16x16x32_bf16(vf, pf, acc[dg], 0, 0, 0);
            }
        }
        __syncthreads();
    }

    lsum += __shfl_xor(lsum, 16);
    lsum += __shfl_xor(lsum, 32);

    {
        int r = tid >> 2, c4 = tid & 3;
        const float* src = Wrv + r * 129 + c4 * 32;
        #pragma unroll
        for (int i = 0; i < 4; i++) {
            float4 f0 = *(const float4*)(src + i * 8);
            float4 f1 = *(const float4*)(src + i * 8 + 4);
            uint4 pkv;
            pkv.x = pk_bf16(f0.x, f0.y);
            pkv.y = pk_bf16(f0.z, f0.w);
            pkv.z = pk_bf16(f1.x, f1.y);
            pkv.w = pk_bf16(f1.z, f1.w);
            *(uint4*)(smem + r * 256 + ((c4 * 64 + i * 16) ^ ((r & 7) << 4))) = pkv;
        }
    }
    __syncthreads();

    #pragma unroll 1
    for (int ks = 0; ks < 4; ks++) {
        uint4 raw = *(const uint4*)((char*)sband + ql * 272 + ks * 64 + hh * 16);
        uint32_t rr[4] = { raw.x, raw.y, raw.z, raw.w };
        uint32_t eu[4];
        #pragma unroll
        for (int i = 0; i < 4; i++) {
            float e0 = exp2_hw(bf2f((uint16_t)(rr[i] & 0xffff)) - MOFF);
            float e1 = exp2_hw(bf2f((uint16_t)(rr[i] >> 16)) - MOFF);
            eu[i] = pk_bf16(e0, e1);
        }
        bf16x8 ef = mk_frag(eu[0], eu[1], eu[2], eu[3]);
        #pragma unroll
        for (int dg = 0; dg < 4; dg++) {
            int dr = dg * 16 + q16;
            bf16x8 wf = *(const bf16x8*)(smem + dr * 256 + ((ks * 64 + hh * 16) ^ ((dr & 7) << 4)));
            acc[dg] = __builtin_amdgcn_mfma_f32_16x16x32_bf16(wf, ef, acc[dg], 0, 0, 0);
        }
    }
    {
        float e128 = exp2_hw(bf2f(sband[ql][128]) - MOFF);
        #pragma unroll
        for (int dg = 0; dg < 4; dg++)
            #pragma unroll
            for (int r = 0; r < 4; r++)
                acc[dg][r] += e128 * Wrv[(dg * 16 + 4 * hh + r) * 129 + 128];
    }

    float inv_l = 1.0f / lsum;
    #pragma unroll
    for (int dg = 0; dg < 4; dg++) {
        fx4 o4 = acc[dg] * inv_l;
        int d0 = dg * 16 + 4 * hh;
        *(fx4*)(out + (size_t)(b * SS + qglob) * (NH * DHH) + h * DHH + d0) = o4;
    }
}

// ---------------------------------------------------------------- launch
extern "C" void kernel_launch(void* const* d_in, const int* in_sizes, int n_in,
                              void* d_out, int out_size, void* d_ws, size_t ws_size,
                              hipStream_t stream) {
    const float* hs    = (const float*)d_in[0];
    const float* amask = (const float*)d_in[1];
    const float* Wq    = (const float*)d_in[2];
    const float* bq    = (const float*)d_in[3];
    const float* Wk    = (const float*)d_in[4];
    const float* bk    = (const float*)d_in[5];
    const float* Wv    = (const float*)d_in[6];
    const float* bv    = (const float*)d_in[7];
    const float* Wrk   = (const float*)d_in[8];
    const float* Wrv   = (const float*)d_in[9];
    float* out = (float*)d_out;

    char* ws = (char*)d_ws;
    uint16_t* Xb   = (uint16_t*)(ws + (0ull  << 20));  // 8 MB  bf16 X [4096][1024]
    uint16_t* Wqb  = (uint16_t*)(ws + (8ull  << 20));  // 2 MB
    uint16_t* Wkb  = (uint16_t*)(ws + (10ull << 20));  // 2 MB
    uint16_t* Wvb  = (uint16_t*)(ws + (12ull << 20));  // 2 MB
    uint16_t* qw   = (uint16_t*)(ws + (14ull << 20));  // 8 MB  [bh][s][d]
    uint16_t* kw   = (uint16_t*)(ws + (22ull << 20));  // 8 MB  [bh][s][d]
    uint16_t* vtw  = (uint16_t*)(ws + (38ull << 20));  // 8 MB  [bh][d][s]
    uint16_t* Wrkb = (uint16_t*)(ws + (46ull << 20));  // 16.5 KB bf16 Wrk

    cvt_all<<<7177, 256, 0, stream>>>(hs, Wq, Wk, Wv, Wrk, Xb, Wqb, Wkb, Wvb, Wrkb);

    proj_gemm3<<<dim3(32, 8, 3), 256, 0, stream>>>(Xb, Wqb, Wkb, Wvb, bq, bk, bv, qw, kw, vtw);

    attn_kernel<<<dim3(16, 64), 256, 0, stream>>>(qw, kw, vtw, amask, Wrkb, Wrv, out);
}